// Round 16
// baseline (192.363 us; speedup 1.0000x reference)
//
#include <hip/hip_runtime.h>
#include <stdint.h>

// QuantizedLinear: out[N,OUT_F] = requant(int8gemm(x, W^T) + bias)
// x: [8192,4096] int8 (pushed int32), W: [4096,4096] int8 (pushed int32)
// out: int8 values stored as int32 (harness reads d_out as np.int32)
//
// r16: cross-block stagger. MFMA blocks its wave (no async MFMA on CDNA), so
// DS/MFMA overlap must come from OTHER waves at a DIFFERENT phase. All
// r7-r15 variants kept every resident wave barrier-aligned -> additive
// LDS+MFMA (measured every round). Fix: 2 independent blocks per CU
// (BN=128, 4 waves, 72 KiB LDS each -> 2 resident; launch_bounds(256,2)
// caps VGPR at 256, acc=128 fits). Unsynchronized block schedules stagger
// naturally -> one block's LDS burst overlaps the other's MFMA burst.
// Body: r7-proven simple tile (plain reads, 1 barrier/tile, counted
// vmcnt(6)), 3-slot ring, 32-row fragment-ordered panels (0 conflicts),
// mfma_i32_32x32x32_i8, setprio, XCD-bijective swizzle.

#define M_DIM 8192
#define N_DIM 4096
#define K_DIM 4096
#define BM 256
#define BN 128
#define NKT2 (K_DIM / 32)            // 128 k-subtiles in panel layout
#define NBLK ((M_DIM / BM) * (N_DIM / BN))   // 32*32 = 1024
#define ASLOT 16384                  // A: 8 rsubs x 2 ksubs x 1024
#define BSLOT 8192                   // B: 4 csubs x 2 ksubs x 1024

using i32x4  = __attribute__((ext_vector_type(4))) int;
using i32x16 = __attribute__((ext_vector_type(16))) int;

typedef const __attribute__((address_space(1))) uint32_t* gptr_t;
typedef __attribute__((address_space(3))) uint32_t* lptr_t;

__device__ __forceinline__ void gload_lds16(const void* g, void* l) {
    __builtin_amdgcn_global_load_lds((gptr_t)g, (lptr_t)l, 16, 0, 0);
}

__device__ __forceinline__ int pack4(i32x4 v) {
    return (int)(((unsigned)v.x & 0xFFu) | (((unsigned)v.y & 0xFFu) << 8) |
                 (((unsigned)v.z & 0xFFu) << 16) | (((unsigned)v.w) << 24));
}

// int32 [rows][K_DIM] -> fragment-ordered panels [rows/32][NKT2][1024]
// block (rb,kt): byte[l*16+j] = (int8)src[rb*32 + (l&31)][kt*32 + (l>>5)*16 + j]
__global__ void pack_panels32_kernel(const int* __restrict__ src, int8_t* __restrict__ dst,
                                     int n_blocks) {
    int gid = blockIdx.x * blockDim.x + threadIdx.x;
    int blk = gid >> 6;
    int l = gid & 63;
    if (blk >= n_blocks) return;
    int rb = blk >> 7;               // / NKT2
    int kt = blk & (NKT2 - 1);
    const i32x4* s4 = (const i32x4*)(src + (size_t)(rb * 32 + (l & 31)) * K_DIM
                                         + kt * 32 + (l >> 5) * 16);
    i32x4 o;
    o.x = pack4(s4[0]); o.y = pack4(s4[1]); o.z = pack4(s4[2]); o.w = pack4(s4[3]);
    *(i32x4*)(dst + (size_t)blk * 1024 + l * 16) = o;
}

#define MFMA32(a, b, c) __builtin_amdgcn_mfma_i32_32x32x32_i8((a), (b), (c), 0, 0, 0)

// Lane-linear fragment reads (bases include wave offset + lane*16).
// Slot/frag offsets fold into ds_read offset immediates. Conflict-free.
#define RA(S, r, k) (*(const i32x4*)(ArdB + (S) * ASLOT + (r) * 2048 + (k) * 1024))
#define RB(S, c, k) (*(const i32x4*)(BrdB + (S) * BSLOT + (c) * 2048 + (k) * 1024))

// Stage tile into slot S: wave stages A rsubs {2w,2w+1} (4 KB) + B csub w
// (2 KB) = 6 x 1KB gload_lds. Running pointers advance 2048 B per K-tile.
#define STAGE(S)                                                              \
    gload_lds16(AgS,         ldsA + (S) * ASLOT + (2 * wave) * 2048);         \
    gload_lds16(AgS  + 1024, ldsA + (S) * ASLOT + (2 * wave) * 2048 + 1024);  \
    gload_lds16(AgS2,        ldsA + (S) * ASLOT + (2 * wave + 1) * 2048);     \
    gload_lds16(AgS2 + 1024, ldsA + (S) * ASLOT + (2 * wave + 1) * 2048 + 1024); \
    gload_lds16(BgS,         ldsB + (S) * BSLOT + wave * 2048);               \
    gload_lds16(BgS  + 1024, ldsB + (S) * BSLOT + wave * 2048 + 1024);        \
    AgS += 2048; AgS2 += 2048; BgS += 2048;

#define VM6 asm volatile("s_waitcnt vmcnt(6)" ::: "memory")
#define VM0 asm volatile("s_waitcnt vmcnt(0)" ::: "memory")

// One K-tile on slot S: 12 plain ds_reads (compiler emits fine-grained
// lgkmcnt), stage of t+2, 16 MFMA under setprio, tail sync, 1 barrier.
#define KTILE(S, STG, TAIL)                                                       \
  { i32x4 a00 = RA(S,0,0), a10 = RA(S,1,0), a20 = RA(S,2,0), a30 = RA(S,3,0);     \
    i32x4 b00 = RB(S,0,0), b10 = RB(S,1,0);                                       \
    i32x4 a01 = RA(S,0,1), a11 = RA(S,1,1), a21 = RA(S,2,1), a31 = RA(S,3,1);     \
    i32x4 b01 = RB(S,0,1), b11 = RB(S,1,1);                                       \
    STG;                                                                          \
    __builtin_amdgcn_s_setprio(1);                                                \
    acc[0][0] = MFMA32(a00, b00, acc[0][0]); acc[0][1] = MFMA32(a00, b10, acc[0][1]); \
    acc[1][0] = MFMA32(a10, b00, acc[1][0]); acc[1][1] = MFMA32(a10, b10, acc[1][1]); \
    acc[2][0] = MFMA32(a20, b00, acc[2][0]); acc[2][1] = MFMA32(a20, b10, acc[2][1]); \
    acc[3][0] = MFMA32(a30, b00, acc[3][0]); acc[3][1] = MFMA32(a30, b10, acc[3][1]); \
    acc[0][0] = MFMA32(a01, b01, acc[0][0]); acc[0][1] = MFMA32(a01, b11, acc[0][1]); \
    acc[1][0] = MFMA32(a11, b01, acc[1][0]); acc[1][1] = MFMA32(a11, b11, acc[1][1]); \
    acc[2][0] = MFMA32(a21, b01, acc[2][0]); acc[2][1] = MFMA32(a21, b11, acc[2][1]); \
    acc[3][0] = MFMA32(a31, b01, acc[3][0]); acc[3][1] = MFMA32(a31, b11, acc[3][1]); \
    __builtin_amdgcn_s_setprio(0);                                                \
    TAIL;                                                                         \
    __builtin_amdgcn_s_barrier(); }

__global__ __launch_bounds__(256, 2)
void qgemm32_kernel(const int8_t* __restrict__ xp, const int8_t* __restrict__ wp,
                    const int* __restrict__ bias, const float* __restrict__ wscale,
                    const float* __restrict__ iscale, const float* __restrict__ oscale,
                    const int* __restrict__ zp, int* __restrict__ out) {
    __shared__ int8_t ldsAll[3 * (ASLOT + BSLOT)];   // 72 KiB -> 2 blocks/CU
    int8_t* ldsA = ldsAll;                 // 3 slots * 16 KiB
    int8_t* ldsB = ldsAll + 3 * ASLOT;     // 3 slots * 8 KiB

    const int tid  = threadIdx.x;
    const int wave = tid >> 6;        // 0..3
    const int lane = tid & 63;

    // XCD-bijective swizzle (NBLK = 1024, divisible by 8)
    int b = blockIdx.x;
    int s = (b & 7) * (NBLK >> 3) + (b >> 3);
    const int bcol = (s & 31) * BN;   // N_DIM/BN = 32
    const int brow = (s >> 5) * BM;   // M_DIM/BM = 32

    const int wr = wave >> 1;         // 0..1  (M half: rsubs wr*4..wr*4+3)
    const int wc = wave & 1;          // 0..1  (N half: csubs wc*2..wc*2+1)

    // staging sources (fragment-ordered panels; advance 2048 B per K-tile)
    const int rb0 = brow >> 5;        // 8 rsubs per tile
    const int cb0 = bcol >> 5;        // 4 csubs per tile
    const int8_t* AgS  = xp + ((size_t)(rb0 + 2 * wave)     * NKT2) * 1024 + lane * 16;
    const int8_t* AgS2 = xp + ((size_t)(rb0 + 2 * wave + 1) * NKT2) * 1024 + lane * 16;
    const int8_t* BgS  = wp + ((size_t)(cb0 + wave)         * NKT2) * 1024 + lane * 16;

    // fragment read bases
    const int8_t* ArdB = ldsA + wr * 8192 + lane * 16;   // wr*4 rsubs * 2048
    const int8_t* BrdB = ldsB + wc * 4096 + lane * 16;   // wc*2 csubs * 2048

    i32x16 acc[4][2] = {};            // 128 VGPR accumulator (128x64 per wave)

    // ---- prologue: stage tile0 -> slot0, tile1 -> slot1; land tile0 ----
    STAGE(0)
    STAGE(1)
    VM6;                              // 12 outstanding -> 6: tile0 landed
    __builtin_amdgcn_s_barrier();

    // ---- main loop: t = 0..59 in 20 groups of 3; tile t reads slot t%3,
    //      stages tile t+2 into slot (t+2)%3, tail vmcnt(6) lands t+1 ----
    for (int i = 0; i < 20; ++i) {
        KTILE(0, STAGE(2), VM6)
        KTILE(1, STAGE(0), VM6)
        KTILE(2, STAGE(1), VM6)
    }
    // ---- t=60 (stage 62->slot2), t=61 (stage 63->slot0) ----
    KTILE(0, STAGE(2), VM6)
    KTILE(1, STAGE(0), VM6)
    // ---- t=62: no stage; drain tile63's staging ----
    KTILE(2, ((void)0), VM0)
    // ---- t=63: final compute (slot0) ----
    KTILE(0, ((void)0), ((void)0))

    // ---- epilogue: out = clip(round((acc + bias) * (is*ws/os) + zp)) as int32 ----
    // 32x32 C/D layout (HW-verified): col = lane&31, row = (reg&3) + 8*(reg>>2) + 4*(lane>>5)
    const float is_v = iscale[0];
    const float os_v = oscale[0];
    const float zpf = (float)zp[0];
    #pragma unroll
    for (int c = 0; c < 2; c++) {
        int col = bcol + wc * 64 + c * 32 + (lane & 31);
        float sf = (is_v * wscale[col]) / os_v;
        int bz = bias[col];
        #pragma unroll
        for (int r = 0; r < 4; r++) {
            int rowb = brow + wr * 128 + r * 32 + 4 * (lane >> 5);
            #pragma unroll
            for (int reg = 0; reg < 16; reg++) {
                int row = rowb + (reg & 3) + 8 * (reg >> 2);
                float v = (float)(acc[r][c][reg] + bz) * sf + zpf;
                v = rintf(v);
                v = fminf(fmaxf(v, -128.0f), 127.0f);
                out[(size_t)row * N_DIM + col] = (int)v;
            }
        }
    }
}

#define MFMA_I8(a, b, c) __builtin_amdgcn_mfma_i32_16x16x64_i8((a), (b), (c), 0, 0, 0)

// Fallback (no workspace): direct int32 consumption, 128^2 tile (round-2 proven).
__global__ void qgemm_fallback(const int* __restrict__ x32, const int* __restrict__ w32,
                               const int* __restrict__ bias, const float* __restrict__ wscale,
                               const float* __restrict__ iscale, const float* __restrict__ oscale,
                               const int* __restrict__ zp, int* __restrict__ out) {
    __shared__ int8_t As[128][64];
    __shared__ int8_t Bs[128][64];
    const int tid  = threadIdx.x;
    const int wave = tid >> 6;
    const int lane = tid & 63;
    int b = blockIdx.x;
    int s = (b & 7) * (gridDim.x >> 3) + (b >> 3);
    const int bcol = (s & 31) * 128;
    const int brow = (s >> 5) * 128;
    const int wr = wave >> 1;
    const int wc = wave & 1;
    i32x4 acc[4][4] = {};
    for (int kt = 0; kt < K_DIM; kt += 64) {
        int row = tid >> 1;
        int h = tid & 1;
        const i32x4* sa = (const i32x4*)(x32 + (size_t)(brow + row) * K_DIM + kt + h * 32);
        const i32x4* sb = (const i32x4*)(w32 + (size_t)(bcol + row) * K_DIM + kt + h * 32);
        int pa[8], pb[8];
        #pragma unroll
        for (int j = 0; j < 8; j++) { pa[j] = pack4(sa[j]); pb[j] = pack4(sb[j]); }
        *(i32x4*)&As[row][h * 32]      = *(i32x4*)&pa[0];
        *(i32x4*)&As[row][h * 32 + 16] = *(i32x4*)&pa[4];
        *(i32x4*)&Bs[row][h * 32]      = *(i32x4*)&pb[0];
        *(i32x4*)&Bs[row][h * 32 + 16] = *(i32x4*)&pb[4];
        __syncthreads();
        i32x4 a_frag[4], b_frag[4];
        #pragma unroll
        for (int m = 0; m < 4; m++)
            a_frag[m] = *(const i32x4*)&As[wr * 64 + m * 16 + (lane & 15)][(lane >> 4) * 16];
        #pragma unroll
        for (int n = 0; n < 4; n++)
            b_frag[n] = *(const i32x4*)&Bs[wc * 64 + n * 16 + (lane & 15)][(lane >> 4) * 16];
        #pragma unroll
        for (int m = 0; m < 4; m++)
            #pragma unroll
            for (int n = 0; n < 4; n++)
                acc[m][n] = MFMA_I8(a_frag[m], b_frag[n], acc[m][n]);
        __syncthreads();
    }
    const float is_v = iscale[0];
    const float os_v = oscale[0];
    const float zpf = (float)zp[0];
    #pragma unroll
    for (int n = 0; n < 4; n++) {
        int col = bcol + wc * 64 + n * 16 + (lane & 15);
        float sf = (is_v * wscale[col]) / os_v;
        int bz = bias[col];
        #pragma unroll
        for (int m = 0; m < 4; m++) {
            int row0 = brow + wr * 64 + m * 16 + (lane >> 4) * 4;
            #pragma unroll
            for (int r = 0; r < 4; r++) {
                float v = (float)(acc[m][n][r] + bz) * sf + zpf;
                v = rintf(v);
                v = fminf(fmaxf(v, -128.0f), 127.0f);
                out[(size_t)(row0 + r) * N_DIM + col] = (int)v;
            }
        }
    }
}

extern "C" void kernel_launch(void* const* d_in, const int* in_sizes, int n_in,
                              void* d_out, int out_size, void* d_ws, size_t ws_size,
                              hipStream_t stream) {
    const int*   x32    = (const int*)d_in[0];
    const int*   w32    = (const int*)d_in[1];
    const int*   bias   = (const int*)d_in[2];
    const float* wscale = (const float*)d_in[3];
    const float* iscale = (const float*)d_in[4];
    const float* oscale = (const float*)d_in[5];
    const int*   zp     = (const int*)d_in[6];
    int* out = (int*)d_out;

    const size_t need = (size_t)M_DIM * K_DIM + (size_t)N_DIM * K_DIM;  // 50.3 MB

    if (ws_size >= need) {
        int8_t* xp = (int8_t*)d_ws;
        int8_t* wp = xp + (size_t)M_DIM * K_DIM;
        const int nblkA = (M_DIM / 32) * NKT2;   // 32768
        const int nblkB = (N_DIM / 32) * NKT2;   // 16384
        pack_panels32_kernel<<<nblkA / 4, 256, 0, stream>>>(x32, xp, nblkA);
        pack_panels32_kernel<<<nblkB / 4, 256, 0, stream>>>(w32, wp, nblkB);
        qgemm32_kernel<<<NBLK, 256, 0, stream>>>(xp, wp, bias, wscale, iscale, oscale, zp, out);
    } else {
        qgemm_fallback<<<2048, 256, 0, stream>>>(x32, w32, bias, wscale, iscale, oscale, zp, out);
    }
}